// Round 1
// baseline (362.539 us; speedup 1.0000x reference)
//
#include <hip/hip_runtime.h>
#include <math.h>

#define NSAMP 4096
#define DIMX  12800

// Layout of the concatenated J matrices (l=1..4) in workspace / LDS:
// l=1: [0,9)  l=2: [9,34)  l=3: [34,83)  l=4: [83,164)
#define JTOT 164

// ---------------------------------------------------------------------------
// Init kernel: recompute J_l = Re(A d^l(pi/2) A^H) in fp64, element-parallel.
// One block of 256 threads; threads 0..163 each own one (l,i,j) element.
// ---------------------------------------------------------------------------
__global__ __launch_bounds__(256) void initJ_kernel(float* __restrict__ Jout) {
    __shared__ double dm[JTOT];
    __shared__ double Ar[JTOT], Ai[JTOT];
    __shared__ double Br[JTOT], Bi[JTOT];

    const int tid = threadIdx.x;
    int l = 0, base = 0, d = 0, ii = 0, jj = 0;
    const bool act = tid < JTOT;
    if (act) {
        if (tid < 9)       { l = 1; base = 0; }
        else if (tid < 34) { l = 2; base = 9; }
        else if (tid < 83) { l = 3; base = 34; }
        else               { l = 4; base = 83; }
        d = 2 * l + 1;
        int loc = tid - base;
        ii = loc / d;           // mp row
        jj = loc - ii * d;      // m col

        // factorials 0..8
        double fact[9];
        fact[0] = 1.0;
        for (int k = 1; k < 9; k++) fact[k] = fact[k - 1] * (double)k;

        const int mp = ii - l, m = jj - l;
        const double num = sqrt(fact[l + mp] * fact[l - mp] * fact[l + m] * fact[l - m]);
        const double c2 = 0.70710678118654752440;  // cos(pi/4) == sin(pi/4)
        double tot = 0.0;
        const int s0 = (m - mp > 0) ? (m - mp) : 0;
        const int s1 = (l + m < l - mp) ? (l + m) : (l - mp);
        for (int s = s0; s <= s1; s++) {
            double den = fact[l + m - s] * fact[s] * fact[mp - m + s] * fact[l - mp - s];
            int etot = (2 * l + m - mp - 2 * s) + (mp - m + 2 * s);  // = 2l, but keep general
            double p = 1.0;
            for (int q = 0; q < etot; q++) p *= c2;
            double sgn = ((mp - m + s) & 1) ? -1.0 : 1.0;
            tot += sgn * (num / den) * p;
        }
        dm[tid] = tot;

        // Real-basis change matrix A (complex), element (ii,jj)
        double ar = 0.0, ai = 0.0;
        const double inv_s2 = 0.70710678118654752440;
        if (ii == l) {
            if (jj == l) ar = 1.0;
        } else if (ii > l) {
            int mm = ii - l;
            if (jj == l + mm)      ar = (mm & 1) ? -inv_s2 : inv_s2;  // (-1)^mm / sqrt2
            else if (jj == l - mm) ar = inv_s2;
        } else {  // ii < l
            int mm = l - ii;
            if (jj == l + mm)      ai = (mm & 1) ? inv_s2 : -inv_s2;  // -1j*(-1)^mm/sqrt2
            else if (jj == l - mm) ai = inv_s2;                        // +1j/sqrt2
        }
        Ar[tid] = ar; Ai[tid] = ai;
    }
    __syncthreads();
    if (act) {  // B = A @ dm (dm real)
        double br = 0.0, bi = 0.0;
        for (int k = 0; k < d; k++) {
            double dv = dm[base + k * d + jj];
            br += Ar[base + ii * d + k] * dv;
            bi += Ai[base + ii * d + k] * dv;
        }
        Br[tid] = br; Bi[tid] = bi;
    }
    __syncthreads();
    if (act) {  // J = Re(B @ A^H)
        double jr = 0.0;
        for (int k = 0; k < d; k++) {
            jr += Br[base + ii * d + k] * Ar[base + jj * d + k]
                + Bi[base + ii * d + k] * Ai[base + jj * d + k];
        }
        Jout[tid] = (float)jr;
    }
}

// ---------------------------------------------------------------------------
// Main kernel: one block per sample. Build D in LDS, then stream x -> out.
// ---------------------------------------------------------------------------
template <int L>
__device__ __forceinline__ void apply_l(const float* __restrict__ xs_base,
                                        float* __restrict__ os_base,
                                        const float* __restrict__ Dl, int tid) {
    constexpr int d = 2 * L + 1;
#pragma unroll
    for (int rep = 0; rep < 2; rep++) {
        const int g = tid + rep * 256;
        const float* xs = xs_base + g * d;
        float v[d];
#pragma unroll
        for (int j = 0; j < d; j++) v[j] = xs[j];
        float r[d];
#pragma unroll
        for (int i = 0; i < d; i++) {
            float acc = 0.0f;
#pragma unroll
            for (int j = 0; j < d; j++) acc = fmaf(Dl[i * d + j], v[j], acc);
            r[i] = acc;
        }
        float* os = os_base + g * d;
#pragma unroll
        for (int i = 0; i < d; i++) os[i] = r[i];
    }
}

__global__ __launch_bounds__(256) void rot_main(
    const float* __restrict__ gamma, const float* __restrict__ beta,
    const float* __restrict__ alpha, const float* __restrict__ x,
    const float* __restrict__ Jws, float* __restrict__ out) {
    __shared__ float sJ[JTOT];
    __shared__ float sD[JTOT];
    __shared__ float sT0[JTOT];
    __shared__ float sT1[JTOT];
    __shared__ float trig[3][10];  // [angle][cos0..cos4, sin0..sin4]

    const int tid = threadIdx.x;
    const int n = blockIdx.x;

    if (tid < JTOT) sJ[tid] = Jws[tid];
    if (tid < 30) {
        int ai = tid / 10, k = tid % 10;
        float ang = (ai == 0) ? gamma[n] : (ai == 1) ? beta[n] : alpha[n];
        trig[ai][k] = (k < 5) ? cosf((float)k * ang) : sinf((float)(k - 5) * ang);
    }
    __syncthreads();

    int l = 0, base = 0, d = 0, ii = 0, jj = 0;
    const bool act = tid < JTOT;
    if (act) {
        if (tid < 9)       { l = 1; base = 0; }
        else if (tid < 34) { l = 2; base = 9; }
        else if (tid < 83) { l = 3; base = 34; }
        else               { l = 4; base = 83; }
        d = 2 * l + 1;
        int loc = tid - base;
        ii = loc / d;
        jj = loc - ii * d;
    }
    // Stage 1: T0 = J^T @ Eg  (Eg: diag cos, antidiag -sin; sin_v[d-1-j] = -sin_v[j])
    if (act) {
        int am = jj - l, aa = (am < 0) ? -am : am;
        float cv = trig[0][aa];
        float sv = (am > 0) ? trig[0][5 + aa] : (am < 0) ? -trig[0][5 + aa] : 0.0f;
        sT0[tid] = sJ[base + jj * d + ii] * cv + sJ[base + (d - 1 - jj) * d + ii] * sv;
    }
    __syncthreads();
    // Stage 2: T1 = Eb @ T0
    if (act) {
        int am = ii - l, aa = (am < 0) ? -am : am;
        float cv = trig[1][aa];
        float sv = (am > 0) ? trig[1][5 + aa] : (am < 0) ? -trig[1][5 + aa] : 0.0f;
        sT1[tid] = cv * sT0[tid] - sv * sT0[base + (d - 1 - ii) * d + jj];
    }
    __syncthreads();
    // Stage 3: T2 = J @ T1 -> sT0 (dense, <=9 MACs)
    if (act) {
        float acc = 0.0f;
        for (int k = 0; k < d; k++)
            acc = fmaf(sJ[base + ii * d + k], sT1[base + k * d + jj], acc);
        sT0[tid] = acc;
    }
    __syncthreads();
    // Stage 4: D = Ea @ T2
    if (act) {
        int am = ii - l, aa = (am < 0) ? -am : am;
        float cv = trig[2][aa];
        float sv = (am > 0) ? trig[2][5 + aa] : (am < 0) ? -trig[2][5 + aa] : 0.0f;
        sD[tid] = cv * sT0[tid] - sv * sT0[base + (d - 1 - ii) * d + jj];
    }
    __syncthreads();

    // Phase 2: apply block-diagonal D to this sample's row.
    const float* xrow = x + (size_t)n * DIMX;
    float* orow = out + (size_t)n * DIMX;

    // l=0: plain copy of 512 floats (256 threads x float2; row base is 16B-aligned)
    {
        const float2* xv = (const float2*)xrow;
        float2* ov = (float2*)orow;
        ov[tid] = xv[tid];
    }
    apply_l<1>(xrow + 512,  orow + 512,  &sD[0],  tid);
    apply_l<2>(xrow + 2048, orow + 2048, &sD[9],  tid);
    apply_l<3>(xrow + 4608, orow + 4608, &sD[34], tid);
    apply_l<4>(xrow + 8192, orow + 8192, &sD[83], tid);
}

extern "C" void kernel_launch(void* const* d_in, const int* in_sizes, int n_in,
                              void* d_out, int out_size, void* d_ws, size_t ws_size,
                              hipStream_t stream) {
    const float* gamma = (const float*)d_in[0];
    const float* beta  = (const float*)d_in[1];
    const float* alpha = (const float*)d_in[2];
    const float* x     = (const float*)d_in[3];
    float* out = (float*)d_out;
    float* Jws = (float*)d_ws;  // 164 floats

    hipLaunchKernelGGL(initJ_kernel, dim3(1), dim3(256), 0, stream, Jws);
    hipLaunchKernelGGL(rot_main, dim3(NSAMP), dim3(256), 0, stream,
                       gamma, beta, alpha, x, Jws, out);
}